// Round 10
// baseline (162.547 us; speedup 1.0000x reference)
//
#include <hip/hip_runtime.h>
#include <hip/hip_bf16.h>
#include <cstdint>
#include <cstddef>

#define NBATCH 8
#define NANCH 25500
#define MAXDET 300
#define NBINS 2048
#define SCAT_BLKS 64

typedef __bf16 bf16x8 __attribute__((ext_vector_type(8)));
typedef float floatx4 __attribute__((ext_vector_type(4)));
typedef unsigned long long ull;

struct __align__(16) bfvec8 { __hip_bfloat16 h[8]; };

__device__ __forceinline__ int conf_bin(float v) {
  unsigned bits = __float_as_uint(v);
  int bin = (int)((bits - 0x3D800000u) >> 14);   // [0.0625,1.0) -> 0..2047
  return bin > (NBINS - 1) ? (NBINS - 1) : bin;
}

// ---------------------------------------------------------------------------
// K1: conf = max_c(cls_c * obj), argmax class, threshold 0.1.
// Blocks 0..32 also zero the ghist+gcnt+ctr1 region (replaces hipMemsetAsync
// whose fill dispatches polluted the timed graph). conf_kernel does NOT
// touch the histogram -> no race with the zeroing.
// ---------------------------------------------------------------------------
#define CONF_TILE 64
__global__ __launch_bounds__(256) void conf_kernel(const float* __restrict__ preds,
                                                   float* __restrict__ conf,
                                                   int* __restrict__ cls,
                                                   int* __restrict__ zmem, int zints,
                                                   int total) {
  if (blockIdx.x < 33) {
    int base = blockIdx.x * 1024;
    #pragma unroll
    for (int k = 0; k < 4; ++k) {
      int i = base + k * 256 + threadIdx.x;
      if (i < zints) zmem[i] = 0;
    }
  }
  __shared__ float s[CONF_TILE * 85];
  int base = blockIdx.x * CONF_TILE;
  int nA = total - base; if (nA > CONF_TILE) nA = CONF_TILE;
  int n4 = (nA * 85) >> 2;
  const float4* g4 = (const float4*)(preds + (size_t)base * 85);
  float4* s4 = (float4*)s;
  for (int i = threadIdx.x; i < n4; i += 256) s4[i] = g4[i];
  __syncthreads();
  int lane16 = threadIdx.x & 15;
  int sub = threadIdx.x >> 4;
  #pragma unroll
  for (int r = 0; r < 4; ++r) {
    int a = r * 16 + sub;
    if (a < nA) {
      const float* row = s + a * 85;
      float obj = row[4];
      float best = -1.0f; int bc = 0;
      #pragma unroll
      for (int j = 0; j < 5; ++j) {
        int c = lane16 * 5 + j;
        float v = row[5 + c] * obj;    // exact IEEE mul, matches reference
        if (v > best) { best = v; bc = c; }
      }
      #pragma unroll
      for (int m = 1; m < 16; m <<= 1) {
        float ov = __shfl_xor(best, m, 64);
        int   oc = __shfl_xor(bc,   m, 64);
        if (ov > best || (ov == best && oc < bc)) { best = ov; bc = oc; }
      }
      if (lane16 == 0) {
        int idx = base + a;
        conf[idx] = (best > 0.1f) ? best : 0.0f;
        cls[idx] = bc;
      }
    }
  }
}

// ---------------------------------------------------------------------------
// K2: scatter_kernel (64 blocks x 256). Per (batch, 1/8-segment):
//  (a) LDS 2048-bin histogram of own conf segment, flush nonzero bins to
//      ghist via device atomics, bump ctr1[b] (+fence).
//  (b) spin until the batch's 8 blocks flushed (64 blocks co-resident).
//  (c) atomic-load full hist, register suffix-scan (deterministic ->
//      identical T/suffix in all blocks), re-scan own segment (L2-hot) and
//      scatter candidates (bin>=T) to slot suffix[bin+1]+atomicAdd(gcnt)
//      with PLAIN stores -- readers are in later kernels.
// ---------------------------------------------------------------------------
__global__ __launch_bounds__(256) void scatter_kernel(const float* __restrict__ conf,
                                                      const float* __restrict__ preds,
                                                      const int* __restrict__ clsg,
                                                      int* __restrict__ ghist,
                                                      int* __restrict__ gcnt,
                                                      int* __restrict__ ctr1,
                                                      float* __restrict__ gV,
                                                      int* __restrict__ gI,
                                                      float4* __restrict__ gBox) {
  #pragma clang fp contract(off)
  __shared__ __align__(16) char smem[8448];
  int bid = blockIdx.x;
  int t = threadIdx.x;
  int b = bid >> 3, seg = bid & 7;
  int* s_h = (int*)smem;              // [2048]: hist, later suffix[bin+1]
  int* shv = (int*)(smem + 8192);     // [0]=T, [4..7]=wave partial sums
  #pragma unroll
  for (int k = 0; k < 8; ++k) s_h[t + k * 256] = 0;
  if (t == 0) shv[0] = NBINS;
  __syncthreads();
  const int N4 = NANCH >> 2;                 // 6375
  int i0 = (N4 * seg) >> 3, i1 = (N4 * (seg + 1)) >> 3;
  const float4* cf4 = (const float4*)(conf + (size_t)b * NANCH);
  for (int i = i0 + t; i < i1; i += 256) {
    float4 v = cf4[i];
    if (v.x > 0.1f) atomicAdd(&s_h[conf_bin(v.x)], 1);
    if (v.y > 0.1f) atomicAdd(&s_h[conf_bin(v.y)], 1);
    if (v.z > 0.1f) atomicAdd(&s_h[conf_bin(v.z)], 1);
    if (v.w > 0.1f) atomicAdd(&s_h[conf_bin(v.w)], 1);
  }
  __syncthreads();
  #pragma unroll
  for (int k = 0; k < 8; ++k) {
    int bin = t + k * 256;
    int c = s_h[bin];
    if (c) atomicAdd(&ghist[b * NBINS + bin], c);
  }
  __syncthreads();
  if (t == 0) {
    __threadfence();
    atomicAdd(&ctr1[b], 1);
    while (atomicAdd(&ctr1[b], 0) < 8) __builtin_amdgcn_s_sleep(2);
    __threadfence();
  }
  __syncthreads();
  // full hist -> register suffix scan (identical in all 8 blocks of b)
  int r[8], suf[8], rs[8];
  int w = t >> 6, lane = t & 63;
  {
    #pragma unroll
    for (int k = 0; k < 8; ++k)
      r[k] = atomicAdd(&ghist[b * NBINS + (w * 8 + k) * 64 + lane], 0);
    int bsum = 0;
    #pragma unroll
    for (int k = 0; k < 8; ++k) {
      int s = r[k];
      #pragma unroll
      for (int d = 1; d < 64; d <<= 1) {
        int o = __shfl_down(s, d, 64);
        if (lane + d < 64) s += o;
      }
      suf[k] = s - r[k];
      rs[k] = __shfl(s, 0, 64);
      bsum += rs[k];
    }
    if (lane == 0) shv[4 + w] = bsum;
  }
  __syncthreads();
  {
    int p1 = shv[5], p2 = shv[6], p3 = shv[7];
    int total = shv[4] + p1 + p2 + p3;
    int target = total < 300 ? total : 300;
    int RS = (w == 0) ? (p1 + p2 + p3) : (w == 1) ? (p2 + p3) : (w == 2) ? p3 : 0;
    int run = RS;
    #pragma unroll
    for (int k = 7; k >= 0; --k) {
      int Sx = run + suf[k] + r[k];
      int Sx1 = Sx - r[k];
      int bin = (w * 8 + k) * 64 + lane;
      s_h[bin] = Sx1;                        // suffix[bin+1] = scatter base
      if (total > 0 && Sx >= target && Sx1 < target) shv[0] = bin;
      run += rs[k];
    }
  }
  __syncthreads();
  int T = shv[0];
  for (int i = i0 + t; i < i1; i += 256) {
    float4 v4 = cf4[i];
    int ib = i * 4;
    float vv[4] = {v4.x, v4.y, v4.z, v4.w};
    #pragma unroll
    for (int q = 0; q < 4; ++q) {
      float v = vv[q];
      if (v > 0.1f) {
        int bin = conf_bin(v);
        if (bin >= T) {
          int slot = s_h[bin] + atomicAdd(&gcnt[b * NBINS + bin], 1);
          int idx = ib + q;
          const float* p = preds + ((size_t)b * NANCH + idx) * 85;
          float cx = p[0], cy = p[1], wq = p[2], hq = p[3];
          float hw2 = wq * 0.5f, hh2 = hq * 0.5f;
          float x1 = cx - hw2, y1 = cy - hh2, x2 = cx + hw2, y2 = cy + hh2;
          int c = clsg[(size_t)b * NANCH + idx];
          size_t g = (size_t)b * NANCH + slot;
          gV[g] = v;
          gI[g] = idx | (c << 20);
          gBox[g] = make_float4(x1, y1, x2, y2);
        }
      }
    }
  }
}

// ---------------------------------------------------------------------------
// K3: fused nms (blocks 0..7) + vectorized 64x64 transposes (blocks 8..).
// The two roles are INDEPENDENT (nms reads only the scatter kernel's output)
// -> no intra-kernel sync; nms hides fully under the transposes.
//  Transpose: float4 global loads (16B/lane), LDS [64][65] scalar staging,
//  bf16x8 16B global stores.
//  NMS (256 thr): register suffix-scan, within-bin rank from gV/gI (plain
//  L2-hit loads), float4-IOU ballot, wave-cooperative ctz suppression.
//  FIX vs r9: mask[][] rows are only WRITTEN for word w >= i>>6 (j>i
//  constraint); suppression must (a) zero-init mask and (b) gate reads to
//  l >= m>>6 -- r9 read unwritten LDS -> garbage keep masks.
//  fp contract OFF (bit-exact IOU).
// ---------------------------------------------------------------------------
struct TransArgs {
  const float* src[6];
  __hip_bfloat16* dst[6];
  int C[6], HW[6], tx[6], tpb[6], start[6];   // tx=tiles along p; tile units
};

__global__ __launch_bounds__(256) void nms_trans_kernel(TransArgs a,
                                                        const float* __restrict__ gV,
                                                        const int* __restrict__ gI,
                                                        const float4* __restrict__ gBox,
                                                        const int* __restrict__ ghist,
                                                        float* __restrict__ boxesWs, int* __restrict__ keepWs,
                                                        const float* __restrict__ orig_hw,
                                                        float* __restrict__ out) {
  #pragma clang fp contract(off)
  __shared__ __align__(16) char smem[30208];
  int bid = blockIdx.x;
  int t = threadIdx.x;

  if (bid >= 8) {
    // ======================= transpose role (64x64) ======================
    float (*tile)[65] = (float(*)[65])smem;    // 16,640 B
    int bid2 = bid - 8;
    int s = 0;
    #pragma unroll
    for (int i = 1; i < 6; ++i) if (bid2 >= a.start[i]) s = i;
    int local = bid2 - a.start[s];
    int C = a.C[s], HW = a.HW[s], txp = a.tx[s], tpb = a.tpb[s];
    int b = local / tpb;
    int rem = local - b * tpb;
    int p0 = (rem % txp) * 64;
    int c0 = (rem / txp) * 64;
    const float* inb = a.src[s] + (size_t)b * C * HW;
    __hip_bfloat16* outb = a.dst[s] + (size_t)b * C * HW;
    int rgrp = t >> 4, cg = t & 15;
    if (p0 + 64 <= HW) {
      #pragma unroll
      for (int k = 0; k < 4; ++k) {
        int r = k * 16 + rgrp;
        float4 v = *(const float4*)(inb + (size_t)(c0 + r) * HW + p0 + cg * 4);
        tile[r][cg * 4 + 0] = v.x; tile[r][cg * 4 + 1] = v.y;
        tile[r][cg * 4 + 2] = v.z; tile[r][cg * 4 + 3] = v.w;
      }
    } else {
      int nvp = HW - p0;
      #pragma unroll
      for (int k = 0; k < 4; ++k) {
        int r = k * 16 + rgrp;
        const float* src = inb + (size_t)(c0 + r) * HW + p0;
        #pragma unroll
        for (int j = 0; j < 4; ++j) {
          int pp = cg * 4 + j;
          tile[r][pp] = (pp < nvp) ? src[pp] : 0.0f;
        }
      }
    }
    __syncthreads();
    int cb = (t & 7) * 8;
    #pragma unroll
    for (int pass = 0; pass < 2; ++pass) {
      int p = pass * 32 + (t >> 3);
      if (p0 + p < HW) {
        bfvec8 o;
        #pragma unroll
        for (int j = 0; j < 8; ++j) o.h[j] = __float2bfloat16(tile[cb + j][p]);
        *(bfvec8*)(outb + (size_t)(p0 + p) * C + c0 + cb) = o;
      }
    }
    return;
  }

  // ============================ NMS role =================================
  // s_h @0 (8192, suffix incl), bo4 @8192 (4800), bxx @12992 (4800),
  // mask @17792 (12000), keepw @29792, nzrow @29832, shv @29872
  int*    s_h  = (int*)smem;
  float4* bo4  = (float4*)(smem + 8192);
  float (*bxx)[4] = (float(*)[4])(smem + 12992);
  ull   (*mask)[5] = (ull(*)[5])(smem + 17792);
  ull* keepw = (ull*)(smem + 29792);
  ull* nzrow = (ull*)(smem + 29832);
  int* shv   = (int*)(smem + 29872);   // [0]=T [1]=total [2]=Kslots [4..7]=sums
  int b = bid;

  for (int i = t; i < 300; i += 256) {
    bo4[i] = make_float4(0.0f, 0.0f, 0.0f, 0.0f);
    bxx[i][0] = 0.0f; bxx[i][1] = 0.0f; bxx[i][2] = 0.0f; bxx[i][3] = 0.0f;
  }
  {
    ull* mflat = (ull*)(smem + 17792);       // zero-init mask[300][5]
    for (int i = t; i < 1500; i += 256) mflat[i] = 0ULL;
  }
  if (t < 5) nzrow[t] = 0ULL;
  if (t == 0) { shv[0] = NBINS; shv[2] = 0; }
  {
    int r[8], suf[8], rs[8];
    int w = t >> 6, lane = t & 63;
    {
      #pragma unroll
      for (int k = 0; k < 8; ++k)
        r[k] = ghist[b * NBINS + (w * 8 + k) * 64 + lane];
      int bsum = 0;
      #pragma unroll
      for (int k = 0; k < 8; ++k) {
        int s = r[k];
        #pragma unroll
        for (int d = 1; d < 64; d <<= 1) {
          int o = __shfl_down(s, d, 64);
          if (lane + d < 64) s += o;
        }
        suf[k] = s - r[k];
        rs[k] = __shfl(s, 0, 64);
        bsum += rs[k];
      }
      if (lane == 0) shv[4 + w] = bsum;
    }
    __syncthreads();
    {
      int p1 = shv[5], p2 = shv[6], p3 = shv[7];
      int total = shv[4] + p1 + p2 + p3;
      int target = total < 300 ? total : 300;
      int RS = (w == 0) ? (p1 + p2 + p3) : (w == 1) ? (p2 + p3) : (w == 2) ? p3 : 0;
      int run = RS;
      #pragma unroll
      for (int k = 7; k >= 0; --k) {
        int Sx = run + suf[k] + r[k];     // suffix[bin] inclusive
        int Sx1 = Sx - r[k];              // suffix[bin+1]
        int bin = (w * 8 + k) * 64 + lane;
        s_h[bin] = Sx;
        if (total > 0 && Sx >= target && Sx1 < target) { shv[0] = bin; shv[2] = Sx; }
        run += rs[k];
      }
      if (t == 0) shv[1] = total;
    }
  }
  __syncthreads();
  int total = shv[1];
  int Kslots = shv[2];
  int nvalid = total < 300 ? total : 300;

  for (int i = t; i < 300; i += 256) {
    if (i >= nvalid) {
      size_t bi = ((size_t)(b * 300 + i)) * 4;
      boxesWs[bi + 0] = 0.0f; boxesWs[bi + 1] = 0.0f;
      boxesWs[bi + 2] = 0.0f; boxesWs[bi + 3] = 0.0f;
    }
  }
  if (t < 5) {
    int n = nvalid - t * 64;
    keepw[t] = (n <= 0) ? 0ULL : (n >= 64 ? ~0ULL : ((1ULL << n) - 1ULL));
  }

  // ---- exact rank within bin segment + gather survivor boxes ----
  {
    const float* vb = gV + (size_t)b * NANCH;
    const int*   ib2 = gI + (size_t)b * NANCH;
    for (int sIdx = t; sIdx < Kslots; sIdx += 256) {
      float v = vb[sIdx];
      unsigned code = (unsigned)ib2[sIdx];
      int id = (int)(code & 0xFFFFFu);
      int bin = conf_bin(v);
      int lo = (bin + 1 < NBINS) ? s_h[bin + 1] : 0;
      int hi = s_h[bin];
      int rank = lo;
      for (int j = lo; j < hi; ++j) {
        float vj = vb[j];
        int ij = ib2[j] & 0xFFFFF;
        int gt = vj > v;
        int eq = (vj == v) & (ij < id);
        rank += gt | eq;
      }
      if (rank < 300) {
        float4 bx = gBox[(size_t)b * NANCH + sIdx];
        bxx[rank][0] = bx.x; bxx[rank][1] = bx.y; bxx[rank][2] = bx.z; bxx[rank][3] = bx.w;
        size_t bi = ((size_t)(b * 300 + rank)) * 4;
        boxesWs[bi + 0] = bx.x; boxesWs[bi + 1] = bx.y;
        boxesWs[bi + 2] = bx.z; boxesWs[bi + 3] = bx.w;
        int c = (int)(code >> 20);
        float off = (float)c * 4096.0f;
        float4 ob; ob.x = bx.x + off; ob.y = bx.y + off; ob.z = bx.z + off; ob.w = bx.w + off;
        bo4[rank] = ob;
      }
    }
  }
  __syncthreads();

  // ---- IOU ballot mask: 4 waves x 10 tasks; ds_read_b128 row broadcast ----
  {
    int wv2 = t >> 6, ln = t & 63;
    for (int task = wv2; task < 10; task += 4) {
      int w2 = task >> 1, half = task & 1;
      int j = w2 * 64 + ln;
      int jc = j < 300 ? j : 0;
      float4 jb = bo4[jc];
      float ja = (jb.z - jb.x) * (jb.w - jb.y);
      bool jv = j < 300;
      int iend = w2 * 64 + 64; if (iend > 300) iend = 300;
      int i0 = half * 150, i1 = i0 + 150; if (i1 > iend) i1 = iend;
      #pragma unroll 4
      for (int i = i0; i < i1; ++i) {
        float4 ib = bo4[i];
        float ai = (ib.z - ib.x) * (ib.w - ib.y);
        float ltx = fmaxf(ib.x, jb.x);
        float lty = fmaxf(ib.y, jb.y);
        float rbx = fminf(ib.z, jb.z);
        float rby = fminf(ib.w, jb.w);
        float wx = fmaxf(rbx - ltx, 0.0f);
        float wy = fmaxf(rby - lty, 0.0f);
        float inter = wx * wy;
        float iou = inter / (ai + ja - inter + 1e-7f);
        ull bal = __ballot(jv && (j > i) && (iou > 0.6f));
        if (ln == 0) {
          mask[i][w2] = bal;
          if (bal) atomicOr(&nzrow[i >> 6], 1ULL << (i & 63));
        }
      }
    }
  }
  __syncthreads();

  // ---- wave-cooperative ctz suppression (wave 0) ----
  if (t < 64) {
    int l = t;
    ull kw_l = (l < 5) ? keepw[l] : 0ULL;
    ull nz_l = (l < 5) ? nzrow[l] : 0ULL;
    ull pend = kw_l & nz_l;
    for (;;) {
      int cand = pend ? (l * 64 + (int)__builtin_ctzll(pend)) : 0x7FFFFFFF;
      int m = cand;
      #pragma unroll
      for (int d = 1; d < 64; d <<= 1) {
        int o = __shfl_xor(m, d, 64);
        m = o < m ? o : m;
      }
      if (m == 0x7FFFFFFF) break;
      // only forward words (l >= m>>6) were written; backward are semantically 0
      ull msk = (l < 5 && l >= (m >> 6)) ? mask[m][l] : 0ULL;
      kw_l &= ~msk;
      if (l == (m >> 6)) pend &= ~(1ULL << (m & 63));
      pend &= ~msk;
      pend &= kw_l;
    }
    if (l < 5) keepw[l] = kw_l;
  }
  __syncthreads();
  for (int i = t; i < 300; i += 256) {
    int kp = (int)((keepw[i >> 6] >> (i & 63)) & 1ULL);
    keepWs[b * 300 + i] = kp;
    float oh = orig_hw[b * 2 + 0], ow = orig_hw[b * 2 + 1];
    float gain = fminf(640.0f / oh, 640.0f / ow);
    float padx = (640.0f - ow * gain) * 0.5f;
    float pady = (640.0f - oh * gain) * 0.5f;
    float x1 = fminf(fmaxf((bxx[i][0] - padx) / gain, 0.0f), ow) / ow;
    float y1 = fminf(fmaxf((bxx[i][1] - pady) / gain, 0.0f), oh) / oh;
    float x2 = fminf(fmaxf((bxx[i][2] - padx) / gain, 0.0f), ow) / ow;
    float y2 = fminf(fmaxf((bxx[i][3] - pady) / gain, 0.0f), oh) / oh;
    size_t o = ((size_t)(b * 300 + i)) * 260;
    out[o + 0] = kp ? x1 : 0.0f;
    out[o + 1] = kp ? y1 : 0.0f;
    out[o + 2] = kp ? x2 : 0.0f;
    out[o + 3] = kp ? y2 : 0.0f;
  }
}

// ---------------------------------------------------------------------------
// K4: ROI-align 1x1 over 4 levels from HWC bf16 features -> bf16 fmat rows.
// XCD-affinity: b = blockIdx.x & 7 so every block of batch b lands on XCD b.
// ---------------------------------------------------------------------------
__global__ __launch_bounds__(256) void roi_kernel(const float* __restrict__ boxes,
                                                  const __hip_bfloat16* __restrict__ fT1, const __hip_bfloat16* __restrict__ fT2,
                                                  const __hip_bfloat16* __restrict__ fT3, const __hip_bfloat16* __restrict__ fT4,
                                                  __hip_bfloat16* __restrict__ f) {
  int b = blockIdx.x & 7;
  int r = blockIdx.x >> 3;
  __shared__ int t_off[4][16];
  __shared__ float t_w[4][16];
  int t = threadIdx.x;
  const int Hs[4] = {80, 40, 20, 10};
  const int Cs[4] = {128, 256, 512, 1024};
  const float ss[4] = {0.125f, 0.0625f, 0.03125f, 0.015625f};
  size_t bbase = ((size_t)(b * 300 + r)) * 4;
  float bx0 = boxes[bbase + 0];
  float by0 = boxes[bbase + 1];
  float bx1 = boxes[bbase + 2];
  float by1 = boxes[bbase + 3];
  if (t < 64) {
    int lv = t >> 4, k = t & 15, pp = k >> 2, nb = k & 3;
    float s = ss[lv];
    int H = Hs[lv], W = Hs[lv], C = Cs[lv];
    float b0 = bx0 * s, b1 = by0 * s, b2 = bx1 * s, b3 = by1 * s;
    float w = fmaxf(b2 - b0, 1.0f), h = fmaxf(b3 - b1, 1.0f);
    const float offv[2] = {0.5f, 1.5f};
    float px = b0 + offv[pp & 1] * (w * 0.5f);
    float py = b1 + offv[pp >> 1] * (h * 0.5f);
    float y = fminf(fmaxf(py, 0.0f), (float)(H - 1));
    float x = fminf(fmaxf(px, 0.0f), (float)(W - 1));
    int y0 = (int)floorf(y), x0 = (int)floorf(x);
    int y1 = min(y0 + 1, H - 1), x1 = min(x0 + 1, W - 1);
    float ly = y - (float)y0, lx = x - (float)x0;
    int yy = (nb & 2) ? y1 : y0;
    int xx = (nb & 1) ? x1 : x0;
    float wy = (nb & 2) ? ly : (1.0f - ly);
    float wx = (nb & 1) ? lx : (1.0f - lx);
    t_off[lv][k] = (yy * W + xx) * C;
    t_w[lv][k] = wy * wx;
  }
  __syncthreads();
  const __hip_bfloat16* bases[4] = {
    fT1 + (size_t)b * 6400 * 128,
    fT2 + (size_t)b * 1600 * 256,
    fT3 + (size_t)b * 400 * 512,
    fT4 + (size_t)b * 100 * 1024
  };
  __hip_bfloat16* frow = f + (size_t)(b * 300 + r) * 1920;
  int cbase = 0;
  #pragma unroll
  for (int lv = 0; lv < 4; ++lv) {
    int C = Cs[lv];
    const __hip_bfloat16* base = bases[lv];
    for (int c = t; c < C; c += 256) {
      float acc = 0.0f;
      #pragma unroll
      for (int k = 0; k < 16; ++k)
        acc += t_w[lv][k] * __bfloat162float(base[t_off[lv][k] + c]);
      frow[cbase + c] = __float2bfloat16(acc * 0.25f);
    }
    cbase += C;
  }
}

// ---------------------------------------------------------------------------
// K5/K6: staged bf16 MFMA GEMM. BM=BN=BK=64, 4 waves/block (each 32x32),
// double-buffered LDS via global_load_lds(16B) with both-sides XOR swizzle.
// ---------------------------------------------------------------------------
#define GLDS16(gp, lp) __builtin_amdgcn_global_load_lds( \
    (const __attribute__((address_space(1))) unsigned int*)(gp), \
    (__attribute__((address_space(3))) unsigned int*)(lp), 16, 0, 0)

__global__ __launch_bounds__(256) void gemm_tile_kernel(const __hip_bfloat16* __restrict__ A,
                                                        const __hip_bfloat16* __restrict__ BT,
                                                        const float* __restrict__ bias,
                                                        __hip_bfloat16* __restrict__ Cb,
                                                        float* __restrict__ Cf,
                                                        const int* __restrict__ keep,
                                                        int M, int N, int K, int ldc, int coff) {
  __shared__ __hip_bfloat16 sA[2][64 * 64];
  __shared__ __hip_bfloat16 sB[2][64 * 64];
  int tid = threadIdx.x;
  int bm = blockIdx.x * 64, bn = blockIdx.y * 64;
  int wave = tid >> 6, lane = tid & 63;
  int wr = wave >> 1, wc = wave & 1;
  int idx16 = lane & 15, kb = lane >> 4;
  floatx4 acc[2][2] = {};
  int nt = K >> 6;

  auto stage = [&](int buf, int t) {
    int k0 = t << 6;
    #pragma unroll
    for (int i = 0; i < 2; ++i) {
      int c = tid + i * 256;
      int row = c >> 3, cc = c & 7;
      int scc = cc ^ (row & 7);
      GLDS16(A + (size_t)(bm + row) * K + k0 + scc * 8,
             (char*)&sA[buf][0] + c * 16);
    }
    #pragma unroll
    for (int i = 0; i < 2; ++i) {
      int c = tid + i * 256;
      int row = c >> 3, cc = c & 7;
      int scc = cc ^ (row & 7);
      GLDS16(BT + (size_t)(bn + row) * K + k0 + scc * 8,
             (char*)&sB[buf][0] + c * 16);
    }
  };

  stage(0, 0);
  asm volatile("s_waitcnt vmcnt(0)" ::: "memory");
  __syncthreads();
  int cur = 0;
  for (int t = 0; t < nt; ++t) {
    if (t + 1 < nt) stage(cur ^ 1, t + 1);
    const char* Ab = (const char*)&sA[cur][0];
    const char* Bb = (const char*)&sB[cur][0];
    #pragma unroll
    for (int s = 0; s < 2; ++s) {
      bf16x8 af[2], bg[2];
      #pragma unroll
      for (int m = 0; m < 2; ++m) {
        int row = wr * 32 + m * 16 + idx16;
        int chunk = s * 4 + kb;
        af[m] = *(const bf16x8*)(Ab + row * 128 + ((chunk ^ (row & 7)) * 16));
      }
      #pragma unroll
      for (int n = 0; n < 2; ++n) {
        int row = wc * 32 + n * 16 + idx16;
        int chunk = s * 4 + kb;
        bg[n] = *(const bf16x8*)(Bb + row * 128 + ((chunk ^ (row & 7)) * 16));
      }
      #pragma unroll
      for (int m = 0; m < 2; ++m)
        #pragma unroll
        for (int n = 0; n < 2; ++n)
          acc[m][n] = __builtin_amdgcn_mfma_f32_16x16x32_bf16(af[m], bg[n], acc[m][n], 0, 0, 0);
    }
    asm volatile("s_waitcnt vmcnt(0)" ::: "memory");
    __syncthreads();
    cur ^= 1;
  }
  int col = lane & 15, rb4 = (lane >> 4) * 4;
  #pragma unroll
  for (int m = 0; m < 2; ++m) {
    #pragma unroll
    for (int n = 0; n < 2; ++n) {
      #pragma unroll
      for (int r = 0; r < 4; ++r) {
        int orow = bm + wr * 32 + m * 16 + rb4 + r;
        int ocol = bn + wc * 32 + n * 16 + col;
        if (orow >= M) continue;
        float v = acc[m][n][r] + bias[ocol];
        v = (v >= 0.0f) ? v : 0.01f * v;
        if (Cb) Cb[(size_t)orow * N + ocol] = __float2bfloat16(v);
        if (Cf) {
          float km = keep ? (keep[orow] ? 1.0f : 0.0f) : 1.0f;
          Cf[(size_t)orow * ldc + coff + ocol] = v * km;
        }
      }
    }
  }
}

// ---------------------------------------------------------------------------
extern "C" void kernel_launch(void* const* d_in, const int* in_sizes, int n_in,
                              void* d_out, int out_size, void* d_ws, size_t ws_size,
                              hipStream_t stream) {
  (void)in_sizes; (void)n_in; (void)out_size; (void)ws_size;
  const float* preds  = (const float*)d_in[0];
  const float* feat1  = (const float*)d_in[1];
  const float* feat2  = (const float*)d_in[2];
  const float* feat3  = (const float*)d_in[3];
  const float* feat4  = (const float*)d_in[4];
  const float* orighw = (const float*)d_in[5];
  const float* W1     = (const float*)d_in[6];
  const float* b1     = (const float*)d_in[7];
  const float* W2     = (const float*)d_in[8];
  const float* b2     = (const float*)d_in[9];
  float* out = (float*)d_out;

  char* ws = (char*)d_ws;
  size_t off = 0;
  auto alloc = [&](size_t bytes) -> void* {
    void* p = ws + off;
    off = (off + bytes + 255) & ~(size_t)255;
    return p;
  };
  const int BN = NBATCH * NANCH;   // 204000
  float*  conf   = (float*)alloc((size_t)BN * 4);
  int*    cls    = (int*)  alloc((size_t)BN * 4);
  float*  gV     = (float*)alloc((size_t)BN * 4);
  int*    gI     = (int*)  alloc((size_t)BN * 4);
  float4* gBox   = (float4*)alloc((size_t)BN * 16);
  // zero-region: ghist + gcnt + ctr1 (contiguous; zeroed by conf_kernel)
  int*    ghist  = (int*)  alloc((size_t)NBATCH * NBINS * 4);   // 65536 B
  int*    gcnt   = (int*)  alloc((size_t)NBATCH * NBINS * 4);   // 65536 B
  int*    ctr1   = (int*)  alloc(256);
  const int zints = NBATCH * NBINS * 2 + 64;                    // 32832 ints
  float*  boxes  = (float*)alloc((size_t)NBATCH * 300 * 4 * 4);
  int*    keep   = (int*)  alloc((size_t)NBATCH * 300 * 4);
  __hip_bfloat16* fT1  = (__hip_bfloat16*)alloc((size_t)NBATCH * 6400 * 128 * 2);
  __hip_bfloat16* fT2  = (__hip_bfloat16*)alloc((size_t)NBATCH * 1600 * 256 * 2);
  __hip_bfloat16* fT3  = (__hip_bfloat16*)alloc((size_t)NBATCH * 400 * 512 * 2);
  __hip_bfloat16* fT4  = (__hip_bfloat16*)alloc((size_t)NBATCH * 100 * 1024 * 2);
  __hip_bfloat16* fmat = (__hip_bfloat16*)alloc((size_t)2400 * 1920 * 2);
  __hip_bfloat16* h1b  = (__hip_bfloat16*)alloc((size_t)2400 * 256 * 2);
  __hip_bfloat16* W1T  = (__hip_bfloat16*)alloc((size_t)256 * 1920 * 2);
  __hip_bfloat16* W2T  = (__hip_bfloat16*)alloc((size_t)256 * 256 * 2);

  conf_kernel<<<(BN + CONF_TILE - 1) / CONF_TILE, 256, 0, stream>>>(preds, conf, cls,
                                                                    ghist, zints, BN);

  scatter_kernel<<<SCAT_BLKS, 256, 0, stream>>>(conf, preds, cls, ghist, gcnt, ctr1,
                                                gV, gI, gBox);

  // fused nms (8 blocks) + vectorized 64x64 transposes
  TransArgs ta;
  ta.src[0] = feat1; ta.dst[0] = fT1; ta.C[0] = 128;  ta.HW[0] = 6400;
  ta.src[1] = feat2; ta.dst[1] = fT2; ta.C[1] = 256;  ta.HW[1] = 1600;
  ta.src[2] = feat3; ta.dst[2] = fT3; ta.C[2] = 512;  ta.HW[2] = 400;
  ta.src[3] = feat4; ta.dst[3] = fT4; ta.C[3] = 1024; ta.HW[3] = 100;
  ta.src[4] = W1;    ta.dst[4] = W1T; ta.C[4] = 1920; ta.HW[4] = 256;
  ta.src[5] = W2;    ta.dst[5] = W2T; ta.C[5] = 256;  ta.HW[5] = 256;
  int n_tiles = 0;
  for (int s = 0; s < 6; ++s) {
    int txp = (ta.HW[s] + 63) / 64;
    int tyc = ta.C[s] / 64;
    int nbatch = (s < 4) ? NBATCH : 1;
    ta.tx[s] = txp;
    ta.tpb[s] = txp * tyc;
    ta.start[s] = n_tiles;
    n_tiles += ta.tpb[s] * nbatch;
  }
  nms_trans_kernel<<<8 + n_tiles, 256, 0, stream>>>(ta, gV, gI, gBox, ghist,
                                                    boxes, keep, orighw, out);

  roi_kernel<<<2400, 256, 0, stream>>>(boxes, fT1, fT2, fT3, fT4, fmat);
  gemm_tile_kernel<<<dim3(38, 4), 256, 0, stream>>>(fmat, W1T, b1, h1b, nullptr, nullptr,
                                                    2400, 256, 1920, 0, 0);
  gemm_tile_kernel<<<dim3(38, 4), 256, 0, stream>>>(h1b, W2T, b2, nullptr, out, keep,
                                                    2400, 256, 256, 260, 4);
}

// Round 11
// 129.677 us; speedup vs baseline: 1.2535x; 1.2535x over previous
//
#include <hip/hip_runtime.h>
#include <hip/hip_bf16.h>
#include <cstdint>
#include <cstddef>

#define NBATCH 8
#define NANCH 25500
#define MAXDET 300
#define NBINS 2048
#define SCAT_BLKS 64

typedef __bf16 bf16x8 __attribute__((ext_vector_type(8)));
typedef float floatx4 __attribute__((ext_vector_type(4)));
typedef unsigned long long ull;

struct __align__(16) bfvec8 { __hip_bfloat16 h[8]; };

__device__ __forceinline__ int conf_bin(float v) {
  unsigned bits = __float_as_uint(v);
  int bin = (int)((bits - 0x3D800000u) >> 14);   // [0.0625,1.0) -> 0..2047
  return bin > (NBINS - 1) ? (NBINS - 1) : bin;
}

// ---------------------------------------------------------------------------
// K1: conf = max_c(cls_c * obj), argmax class, threshold 0.1.
// Blocks 0..32 also zero the ghist+gcnt+ctr1 region (replaces hipMemsetAsync
// whose fill dispatches polluted the timed graph).
// ---------------------------------------------------------------------------
#define CONF_TILE 64
__global__ __launch_bounds__(256) void conf_kernel(const float* __restrict__ preds,
                                                   float* __restrict__ conf,
                                                   int* __restrict__ cls,
                                                   int* __restrict__ zmem, int zints,
                                                   int total) {
  if (blockIdx.x < 33) {
    int base = blockIdx.x * 1024;
    #pragma unroll
    for (int k = 0; k < 4; ++k) {
      int i = base + k * 256 + threadIdx.x;
      if (i < zints) zmem[i] = 0;
    }
  }
  __shared__ float s[CONF_TILE * 85];
  int base = blockIdx.x * CONF_TILE;
  int nA = total - base; if (nA > CONF_TILE) nA = CONF_TILE;
  int n4 = (nA * 85) >> 2;
  const float4* g4 = (const float4*)(preds + (size_t)base * 85);
  float4* s4 = (float4*)s;
  for (int i = threadIdx.x; i < n4; i += 256) s4[i] = g4[i];
  __syncthreads();
  int lane16 = threadIdx.x & 15;
  int sub = threadIdx.x >> 4;
  #pragma unroll
  for (int r = 0; r < 4; ++r) {
    int a = r * 16 + sub;
    if (a < nA) {
      const float* row = s + a * 85;
      float obj = row[4];
      float best = -1.0f; int bc = 0;
      #pragma unroll
      for (int j = 0; j < 5; ++j) {
        int c = lane16 * 5 + j;
        float v = row[5 + c] * obj;    // exact IEEE mul, matches reference
        if (v > best) { best = v; bc = c; }
      }
      #pragma unroll
      for (int m = 1; m < 16; m <<= 1) {
        float ov = __shfl_xor(best, m, 64);
        int   oc = __shfl_xor(bc,   m, 64);
        if (ov > best || (ov == best && oc < bc)) { best = ov; bc = oc; }
      }
      if (lane16 == 0) {
        int idx = base + a;
        conf[idx] = (best > 0.1f) ? best : 0.0f;
        cls[idx] = bc;
      }
    }
  }
}

// ---------------------------------------------------------------------------
// K2: scatter_kernel (64 blocks x 256). Per (batch, 1/8-segment):
//  LDS 2048-bin histogram -> ghist atomics -> ctr1 bump -> spin for batch's
//  8 blocks -> register suffix-scan (deterministic, identical in all
//  blocks) -> re-scan own segment and scatter candidates (bin>=T) to slot
//  suffix[bin+1]+atomicAdd(gcnt) with PLAIN stores (readers: next kernel).
// ---------------------------------------------------------------------------
__global__ __launch_bounds__(256) void scatter_kernel(const float* __restrict__ conf,
                                                      const float* __restrict__ preds,
                                                      const int* __restrict__ clsg,
                                                      int* __restrict__ ghist,
                                                      int* __restrict__ gcnt,
                                                      int* __restrict__ ctr1,
                                                      float* __restrict__ gV,
                                                      int* __restrict__ gI,
                                                      float4* __restrict__ gBox) {
  #pragma clang fp contract(off)
  __shared__ __align__(16) char smem[8448];
  int bid = blockIdx.x;
  int t = threadIdx.x;
  int b = bid >> 3, seg = bid & 7;
  int* s_h = (int*)smem;              // [2048]: hist, later suffix[bin+1]
  int* shv = (int*)(smem + 8192);     // [0]=T, [4..7]=wave partial sums
  #pragma unroll
  for (int k = 0; k < 8; ++k) s_h[t + k * 256] = 0;
  if (t == 0) shv[0] = NBINS;
  __syncthreads();
  const int N4 = NANCH >> 2;                 // 6375
  int i0 = (N4 * seg) >> 3, i1 = (N4 * (seg + 1)) >> 3;
  const float4* cf4 = (const float4*)(conf + (size_t)b * NANCH);
  for (int i = i0 + t; i < i1; i += 256) {
    float4 v = cf4[i];
    if (v.x > 0.1f) atomicAdd(&s_h[conf_bin(v.x)], 1);
    if (v.y > 0.1f) atomicAdd(&s_h[conf_bin(v.y)], 1);
    if (v.z > 0.1f) atomicAdd(&s_h[conf_bin(v.z)], 1);
    if (v.w > 0.1f) atomicAdd(&s_h[conf_bin(v.w)], 1);
  }
  __syncthreads();
  #pragma unroll
  for (int k = 0; k < 8; ++k) {
    int bin = t + k * 256;
    int c = s_h[bin];
    if (c) atomicAdd(&ghist[b * NBINS + bin], c);
  }
  __syncthreads();
  if (t == 0) {
    __threadfence();
    atomicAdd(&ctr1[b], 1);
    while (atomicAdd(&ctr1[b], 0) < 8) __builtin_amdgcn_s_sleep(2);
    __threadfence();
  }
  __syncthreads();
  // full hist -> register suffix scan (identical in all 8 blocks of b)
  int r[8], suf[8], rs[8];
  int w = t >> 6, lane = t & 63;
  {
    #pragma unroll
    for (int k = 0; k < 8; ++k)
      r[k] = atomicAdd(&ghist[b * NBINS + (w * 8 + k) * 64 + lane], 0);
    int bsum = 0;
    #pragma unroll
    for (int k = 0; k < 8; ++k) {
      int s = r[k];
      #pragma unroll
      for (int d = 1; d < 64; d <<= 1) {
        int o = __shfl_down(s, d, 64);
        if (lane + d < 64) s += o;
      }
      suf[k] = s - r[k];
      rs[k] = __shfl(s, 0, 64);
      bsum += rs[k];
    }
    if (lane == 0) shv[4 + w] = bsum;
  }
  __syncthreads();
  {
    int p1 = shv[5], p2 = shv[6], p3 = shv[7];
    int total = shv[4] + p1 + p2 + p3;
    int target = total < 300 ? total : 300;
    int RS = (w == 0) ? (p1 + p2 + p3) : (w == 1) ? (p2 + p3) : (w == 2) ? p3 : 0;
    int run = RS;
    #pragma unroll
    for (int k = 7; k >= 0; --k) {
      int Sx = run + suf[k] + r[k];
      int Sx1 = Sx - r[k];
      int bin = (w * 8 + k) * 64 + lane;
      s_h[bin] = Sx1;                        // suffix[bin+1] = scatter base
      if (total > 0 && Sx >= target && Sx1 < target) shv[0] = bin;
      run += rs[k];
    }
  }
  __syncthreads();
  int T = shv[0];
  for (int i = i0 + t; i < i1; i += 256) {
    float4 v4 = cf4[i];
    int ib = i * 4;
    float vv[4] = {v4.x, v4.y, v4.z, v4.w};
    #pragma unroll
    for (int q = 0; q < 4; ++q) {
      float v = vv[q];
      if (v > 0.1f) {
        int bin = conf_bin(v);
        if (bin >= T) {
          int slot = s_h[bin] + atomicAdd(&gcnt[b * NBINS + bin], 1);
          int idx = ib + q;
          const float* p = preds + ((size_t)b * NANCH + idx) * 85;
          float cx = p[0], cy = p[1], wq = p[2], hq = p[3];
          float hw2 = wq * 0.5f, hh2 = hq * 0.5f;
          float x1 = cx - hw2, y1 = cy - hh2, x2 = cx + hw2, y2 = cy + hh2;
          int c = clsg[(size_t)b * NANCH + idx];
          size_t g = (size_t)b * NANCH + slot;
          gV[g] = v;
          gI[g] = idx | (c << 20);
          gBox[g] = make_float4(x1, y1, x2, y2);
        }
      }
    }
  }
}

// ---------------------------------------------------------------------------
// K3: fused @1024 threads: blocks 0..7 = NMS (r8's proven 1024-thread body,
// ~22us: 10-wave IOU, serial suppression); blocks 8.. = FOUR vectorized
// 64x64 transpose tiles per block (one per 256-thread group, private 16.6KB
// LDS slice; float4 loads, bf16x8 stores). Roles are independent (NMS reads
// only scatter_kernel output) -> NMS hides under transposes; 66.5KB LDS ->
// 2 blocks/CU = 32 waves (max occupancy). fp contract OFF (bit-exact IOU).
// ---------------------------------------------------------------------------
struct TransArgs {
  const float* src[6];
  __hip_bfloat16* dst[6];
  int C[6], HW[6], tx[6], tpb[6], start[6];   // tx=tiles along p; tile units
};

__global__ __launch_bounds__(1024) void nms_trans_kernel(TransArgs a,
                                                         const float* __restrict__ gV,
                                                         const int* __restrict__ gI,
                                                         const float4* __restrict__ gBox,
                                                         const int* __restrict__ ghist,
                                                         float* __restrict__ boxesWs, int* __restrict__ keepWs,
                                                         const float* __restrict__ orig_hw,
                                                         float* __restrict__ out,
                                                         int n_trans_tiles) {
  #pragma clang fp contract(off)
  __shared__ __align__(16) char smem[66560];
  int bid = blockIdx.x;
  int t = threadIdx.x;

  if (bid >= 8) {
    // ================== transpose role: 4x 64x64 tiles ===================
    int g = t >> 8, lt = t & 255;
    int gt = (bid - 8) * 4 + g;
    float (*tile)[65] = (float(*)[65])(smem + g * 16640);
    bool act = gt < n_trans_tiles;
    int C = 0, HW = 0, p0 = 0, c0 = 0;
    const float* inb = nullptr;
    __hip_bfloat16* outb = nullptr;
    if (act) {
      int s = 0;
      #pragma unroll
      for (int i = 1; i < 6; ++i) if (gt >= a.start[i]) s = i;
      int local = gt - a.start[s];
      C = a.C[s]; HW = a.HW[s];
      int txp = a.tx[s], tpb = a.tpb[s];
      int b = local / tpb;
      int rem = local - b * tpb;
      p0 = (rem % txp) * 64;
      c0 = (rem / txp) * 64;
      inb = a.src[s] + (size_t)b * C * HW;
      outb = a.dst[s] + (size_t)b * C * HW;
      int rgrp = lt >> 4, cg = lt & 15;
      if (p0 + 64 <= HW) {
        #pragma unroll
        for (int k = 0; k < 4; ++k) {
          int r = k * 16 + rgrp;
          float4 v = *(const float4*)(inb + (size_t)(c0 + r) * HW + p0 + cg * 4);
          tile[r][cg * 4 + 0] = v.x; tile[r][cg * 4 + 1] = v.y;
          tile[r][cg * 4 + 2] = v.z; tile[r][cg * 4 + 3] = v.w;
        }
      } else {
        int nvp = HW - p0;
        #pragma unroll
        for (int k = 0; k < 4; ++k) {
          int r = k * 16 + rgrp;
          const float* src = inb + (size_t)(c0 + r) * HW + p0;
          #pragma unroll
          for (int j = 0; j < 4; ++j) {
            int pp = cg * 4 + j;
            tile[r][pp] = (pp < nvp) ? src[pp] : 0.0f;
          }
        }
      }
    }
    __syncthreads();
    if (act) {
      int cb = (lt & 7) * 8;
      #pragma unroll
      for (int pass = 0; pass < 2; ++pass) {
        int p = pass * 32 + (lt >> 3);
        if (p0 + p < HW) {
          bfvec8 o;
          #pragma unroll
          for (int j = 0; j < 8; ++j) o.h[j] = __float2bfloat16(tile[cb + j][p]);
          *(bfvec8*)(outb + (size_t)(p0 + p) * C + c0 + cb) = o;
        }
      }
    }
    return;
  }

  // ===================== NMS role (r8 body, 1024 thr) ====================
  // s_h @0 (8192, suffix incl), bo4 @8192 (4800), bxx @12992 (4800),
  // mask @17792 (12000), keepw @29792, nzrow @29832, shv @29872
  int*    s_h  = (int*)smem;
  float4* bo4  = (float4*)(smem + 8192);
  float (*bxx)[4] = (float(*)[4])(smem + 12992);
  ull   (*mask)[5] = (ull(*)[5])(smem + 17792);
  ull* keepw = (ull*)(smem + 29792);
  ull* nzrow = (ull*)(smem + 29832);
  int* shv   = (int*)(smem + 29872);   // [0]=T [1]=total [2]=Kslots [4..7]=sums
  int b = bid;

  if (t < 300) {
    bo4[t] = make_float4(0.0f, 0.0f, 0.0f, 0.0f);
    bxx[t][0] = 0.0f; bxx[t][1] = 0.0f; bxx[t][2] = 0.0f; bxx[t][3] = 0.0f;
  }
  if (t < 5) nzrow[t] = 0ULL;
  if (t == 0) { shv[0] = NBINS; shv[2] = 0; }
  {
    int r[8], suf[8], rs[8];
    int w = t >> 6, lane = t & 63;
    if (t < 256) {
      #pragma unroll
      for (int k = 0; k < 8; ++k)
        r[k] = ghist[b * NBINS + (w * 8 + k) * 64 + lane];
      int bsum = 0;
      #pragma unroll
      for (int k = 0; k < 8; ++k) {
        int s = r[k];
        #pragma unroll
        for (int d = 1; d < 64; d <<= 1) {
          int o = __shfl_down(s, d, 64);
          if (lane + d < 64) s += o;
        }
        suf[k] = s - r[k];
        rs[k] = __shfl(s, 0, 64);
        bsum += rs[k];
      }
      if (lane == 0) shv[4 + w] = bsum;
    }
    __syncthreads();
    if (t < 256) {
      int p1 = shv[5], p2 = shv[6], p3 = shv[7];
      int total = shv[4] + p1 + p2 + p3;
      int target = total < 300 ? total : 300;
      int RS = (w == 0) ? (p1 + p2 + p3) : (w == 1) ? (p2 + p3) : (w == 2) ? p3 : 0;
      int run = RS;
      #pragma unroll
      for (int k = 7; k >= 0; --k) {
        int Sx = run + suf[k] + r[k];     // suffix[bin] inclusive
        int Sx1 = Sx - r[k];              // suffix[bin+1]
        int bin = (w * 8 + k) * 64 + lane;
        s_h[bin] = Sx;
        if (total > 0 && Sx >= target && Sx1 < target) { shv[0] = bin; shv[2] = Sx; }
        run += rs[k];
      }
      if (t == 0) shv[1] = total;
    }
  }
  __syncthreads();
  int total = shv[1];
  int Kslots = shv[2];
  int nvalid = total < 300 ? total : 300;

  if (t >= nvalid && t < 300) {
    size_t bi = ((size_t)(b * 300 + t)) * 4;
    boxesWs[bi + 0] = 0.0f; boxesWs[bi + 1] = 0.0f;
    boxesWs[bi + 2] = 0.0f; boxesWs[bi + 3] = 0.0f;
  }
  if (t < 5) {
    int n = nvalid - t * 64;
    keepw[t] = (n <= 0) ? 0ULL : (n >= 64 ? ~0ULL : ((1ULL << n) - 1ULL));
  }

  // ---- exact rank within bin segment + gather survivor boxes ----
  {
    const float* vb = gV + (size_t)b * NANCH;
    const int*   ib2 = gI + (size_t)b * NANCH;
    for (int sIdx = t; sIdx < Kslots; sIdx += 1024) {
      float v = vb[sIdx];
      unsigned code = (unsigned)ib2[sIdx];
      int id = (int)(code & 0xFFFFFu);
      int bin = conf_bin(v);
      int lo = (bin + 1 < NBINS) ? s_h[bin + 1] : 0;
      int hi = s_h[bin];
      int rank = lo;
      for (int j = lo; j < hi; ++j) {
        float vj = vb[j];
        int ij = ib2[j] & 0xFFFFF;
        int gt = vj > v;
        int eq = (vj == v) & (ij < id);
        rank += gt | eq;
      }
      if (rank < 300) {
        float4 bx = gBox[(size_t)b * NANCH + sIdx];
        bxx[rank][0] = bx.x; bxx[rank][1] = bx.y; bxx[rank][2] = bx.z; bxx[rank][3] = bx.w;
        size_t bi = ((size_t)(b * 300 + rank)) * 4;
        boxesWs[bi + 0] = bx.x; boxesWs[bi + 1] = bx.y;
        boxesWs[bi + 2] = bx.z; boxesWs[bi + 3] = bx.w;
        int c = (int)(code >> 20);
        float off = (float)c * 4096.0f;
        float4 ob; ob.x = bx.x + off; ob.y = bx.y + off; ob.z = bx.z + off; ob.w = bx.w + off;
        bo4[rank] = ob;
      }
    }
  }
  __syncthreads();

  // ---- IOU ballot mask: 10 waves; one ds_read_b128 broadcast per row ----
  {
    int wv2 = t >> 6, ln = t & 63;
    if (wv2 < 10) {
      int w2 = wv2 >> 1, half = wv2 & 1;
      int j = w2 * 64 + ln;
      int jc = j < 300 ? j : 0;
      float4 jb = bo4[jc];
      float ja = (jb.z - jb.x) * (jb.w - jb.y);
      bool jv = j < 300;
      int iend = w2 * 64 + 64; if (iend > 300) iend = 300;
      int i0 = half * 150, i1 = i0 + 150; if (i1 > iend) i1 = iend;
      #pragma unroll 4
      for (int i = i0; i < i1; ++i) {
        float4 ib = bo4[i];
        float ai = (ib.z - ib.x) * (ib.w - ib.y);
        float ltx = fmaxf(ib.x, jb.x);
        float lty = fmaxf(ib.y, jb.y);
        float rbx = fminf(ib.z, jb.z);
        float rby = fminf(ib.w, jb.w);
        float wx = fmaxf(rbx - ltx, 0.0f);
        float wy = fmaxf(rby - lty, 0.0f);
        float inter = wx * wy;
        float iou = inter / (ai + ja - inter + 1e-7f);
        ull bal = __ballot(jv && (j > i) && (iou > 0.6f));
        if (ln == 0) {
          mask[i][w2] = bal;
          if (bal) atomicOr(&nzrow[i >> 6], 1ULL << (i & 63));
        }
      }
    }
  }
  __syncthreads();
  if (t == 0) {
    ull kw[5], nz[5];
    #pragma unroll
    for (int w2 = 0; w2 < 5; ++w2) { kw[w2] = keepw[w2]; nz[w2] = nzrow[w2]; }
    #pragma unroll
    for (int w2 = 0; w2 < 5; ++w2) {
      ull p = kw[w2] & nz[w2];
      while (p) {
        int l2 = __builtin_ctzll(p);
        p &= p - 1;
        int i = w2 * 64 + l2;
        for (int w3 = w2; w3 < 5; ++w3) {
          ull m = mask[i][w3];
          kw[w3] &= ~m;
          if (w3 == w2) p &= ~m;
        }
      }
    }
    #pragma unroll
    for (int w2 = 0; w2 < 5; ++w2) keepw[w2] = kw[w2];
  }
  __syncthreads();
  if (t < 300) {
    int kp = (int)((keepw[t >> 6] >> (t & 63)) & 1ULL);
    keepWs[b * 300 + t] = kp;
    float oh = orig_hw[b * 2 + 0], ow = orig_hw[b * 2 + 1];
    float gain = fminf(640.0f / oh, 640.0f / ow);
    float padx = (640.0f - ow * gain) * 0.5f;
    float pady = (640.0f - oh * gain) * 0.5f;
    float x1 = fminf(fmaxf((bxx[t][0] - padx) / gain, 0.0f), ow) / ow;
    float y1 = fminf(fmaxf((bxx[t][1] - pady) / gain, 0.0f), oh) / oh;
    float x2 = fminf(fmaxf((bxx[t][2] - padx) / gain, 0.0f), ow) / ow;
    float y2 = fminf(fmaxf((bxx[t][3] - pady) / gain, 0.0f), oh) / oh;
    size_t o = ((size_t)(b * 300 + t)) * 260;
    out[o + 0] = kp ? x1 : 0.0f;
    out[o + 1] = kp ? y1 : 0.0f;
    out[o + 2] = kp ? x2 : 0.0f;
    out[o + 3] = kp ? y2 : 0.0f;
  }
}

// ---------------------------------------------------------------------------
// K4: ROI-align 1x1 over 4 levels from HWC bf16 features -> bf16 fmat rows.
// XCD-affinity: b = blockIdx.x & 7 so every block of batch b lands on XCD b.
// ---------------------------------------------------------------------------
__global__ __launch_bounds__(256) void roi_kernel(const float* __restrict__ boxes,
                                                  const __hip_bfloat16* __restrict__ fT1, const __hip_bfloat16* __restrict__ fT2,
                                                  const __hip_bfloat16* __restrict__ fT3, const __hip_bfloat16* __restrict__ fT4,
                                                  __hip_bfloat16* __restrict__ f) {
  int b = blockIdx.x & 7;
  int r = blockIdx.x >> 3;
  __shared__ int t_off[4][16];
  __shared__ float t_w[4][16];
  int t = threadIdx.x;
  const int Hs[4] = {80, 40, 20, 10};
  const int Cs[4] = {128, 256, 512, 1024};
  const float ss[4] = {0.125f, 0.0625f, 0.03125f, 0.015625f};
  size_t bbase = ((size_t)(b * 300 + r)) * 4;
  float bx0 = boxes[bbase + 0];
  float by0 = boxes[bbase + 1];
  float bx1 = boxes[bbase + 2];
  float by1 = boxes[bbase + 3];
  if (t < 64) {
    int lv = t >> 4, k = t & 15, pp = k >> 2, nb = k & 3;
    float s = ss[lv];
    int H = Hs[lv], W = Hs[lv], C = Cs[lv];
    float b0 = bx0 * s, b1 = by0 * s, b2 = bx1 * s, b3 = by1 * s;
    float w = fmaxf(b2 - b0, 1.0f), h = fmaxf(b3 - b1, 1.0f);
    const float offv[2] = {0.5f, 1.5f};
    float px = b0 + offv[pp & 1] * (w * 0.5f);
    float py = b1 + offv[pp >> 1] * (h * 0.5f);
    float y = fminf(fmaxf(py, 0.0f), (float)(H - 1));
    float x = fminf(fmaxf(px, 0.0f), (float)(W - 1));
    int y0 = (int)floorf(y), x0 = (int)floorf(x);
    int y1 = min(y0 + 1, H - 1), x1 = min(x0 + 1, W - 1);
    float ly = y - (float)y0, lx = x - (float)x0;
    int yy = (nb & 2) ? y1 : y0;
    int xx = (nb & 1) ? x1 : x0;
    float wy = (nb & 2) ? ly : (1.0f - ly);
    float wx = (nb & 1) ? lx : (1.0f - lx);
    t_off[lv][k] = (yy * W + xx) * C;
    t_w[lv][k] = wy * wx;
  }
  __syncthreads();
  const __hip_bfloat16* bases[4] = {
    fT1 + (size_t)b * 6400 * 128,
    fT2 + (size_t)b * 1600 * 256,
    fT3 + (size_t)b * 400 * 512,
    fT4 + (size_t)b * 100 * 1024
  };
  __hip_bfloat16* frow = f + (size_t)(b * 300 + r) * 1920;
  int cbase = 0;
  #pragma unroll
  for (int lv = 0; lv < 4; ++lv) {
    int C = Cs[lv];
    const __hip_bfloat16* base = bases[lv];
    for (int c = t; c < C; c += 256) {
      float acc = 0.0f;
      #pragma unroll
      for (int k = 0; k < 16; ++k)
        acc += t_w[lv][k] * __bfloat162float(base[t_off[lv][k] + c]);
      frow[cbase + c] = __float2bfloat16(acc * 0.25f);
    }
    cbase += C;
  }
}

// ---------------------------------------------------------------------------
// K5/K6: staged bf16 MFMA GEMM. BM=BN=BK=64, 4 waves/block (each 32x32),
// double-buffered LDS via global_load_lds(16B) with both-sides XOR swizzle.
// ---------------------------------------------------------------------------
#define GLDS16(gp, lp) __builtin_amdgcn_global_load_lds( \
    (const __attribute__((address_space(1))) unsigned int*)(gp), \
    (__attribute__((address_space(3))) unsigned int*)(lp), 16, 0, 0)

__global__ __launch_bounds__(256) void gemm_tile_kernel(const __hip_bfloat16* __restrict__ A,
                                                        const __hip_bfloat16* __restrict__ BT,
                                                        const float* __restrict__ bias,
                                                        __hip_bfloat16* __restrict__ Cb,
                                                        float* __restrict__ Cf,
                                                        const int* __restrict__ keep,
                                                        int M, int N, int K, int ldc, int coff) {
  __shared__ __hip_bfloat16 sA[2][64 * 64];
  __shared__ __hip_bfloat16 sB[2][64 * 64];
  int tid = threadIdx.x;
  int bm = blockIdx.x * 64, bn = blockIdx.y * 64;
  int wave = tid >> 6, lane = tid & 63;
  int wr = wave >> 1, wc = wave & 1;
  int idx16 = lane & 15, kb = lane >> 4;
  floatx4 acc[2][2] = {};
  int nt = K >> 6;

  auto stage = [&](int buf, int t) {
    int k0 = t << 6;
    #pragma unroll
    for (int i = 0; i < 2; ++i) {
      int c = tid + i * 256;
      int row = c >> 3, cc = c & 7;
      int scc = cc ^ (row & 7);
      GLDS16(A + (size_t)(bm + row) * K + k0 + scc * 8,
             (char*)&sA[buf][0] + c * 16);
    }
    #pragma unroll
    for (int i = 0; i < 2; ++i) {
      int c = tid + i * 256;
      int row = c >> 3, cc = c & 7;
      int scc = cc ^ (row & 7);
      GLDS16(BT + (size_t)(bn + row) * K + k0 + scc * 8,
             (char*)&sB[buf][0] + c * 16);
    }
  };

  stage(0, 0);
  asm volatile("s_waitcnt vmcnt(0)" ::: "memory");
  __syncthreads();
  int cur = 0;
  for (int t = 0; t < nt; ++t) {
    if (t + 1 < nt) stage(cur ^ 1, t + 1);
    const char* Ab = (const char*)&sA[cur][0];
    const char* Bb = (const char*)&sB[cur][0];
    #pragma unroll
    for (int s = 0; s < 2; ++s) {
      bf16x8 af[2], bg[2];
      #pragma unroll
      for (int m = 0; m < 2; ++m) {
        int row = wr * 32 + m * 16 + idx16;
        int chunk = s * 4 + kb;
        af[m] = *(const bf16x8*)(Ab + row * 128 + ((chunk ^ (row & 7)) * 16));
      }
      #pragma unroll
      for (int n = 0; n < 2; ++n) {
        int row = wc * 32 + n * 16 + idx16;
        int chunk = s * 4 + kb;
        bg[n] = *(const bf16x8*)(Bb + row * 128 + ((chunk ^ (row & 7)) * 16));
      }
      #pragma unroll
      for (int m = 0; m < 2; ++m)
        #pragma unroll
        for (int n = 0; n < 2; ++n)
          acc[m][n] = __builtin_amdgcn_mfma_f32_16x16x32_bf16(af[m], bg[n], acc[m][n], 0, 0, 0);
    }
    asm volatile("s_waitcnt vmcnt(0)" ::: "memory");
    __syncthreads();
    cur ^= 1;
  }
  int col = lane & 15, rb4 = (lane >> 4) * 4;
  #pragma unroll
  for (int m = 0; m < 2; ++m) {
    #pragma unroll
    for (int n = 0; n < 2; ++n) {
      #pragma unroll
      for (int r = 0; r < 4; ++r) {
        int orow = bm + wr * 32 + m * 16 + rb4 + r;
        int ocol = bn + wc * 32 + n * 16 + col;
        if (orow >= M) continue;
        float v = acc[m][n][r] + bias[ocol];
        v = (v >= 0.0f) ? v : 0.01f * v;
        if (Cb) Cb[(size_t)orow * N + ocol] = __float2bfloat16(v);
        if (Cf) {
          float km = keep ? (keep[orow] ? 1.0f : 0.0f) : 1.0f;
          Cf[(size_t)orow * ldc + coff + ocol] = v * km;
        }
      }
    }
  }
}

// ---------------------------------------------------------------------------
extern "C" void kernel_launch(void* const* d_in, const int* in_sizes, int n_in,
                              void* d_out, int out_size, void* d_ws, size_t ws_size,
                              hipStream_t stream) {
  (void)in_sizes; (void)n_in; (void)out_size; (void)ws_size;
  const float* preds  = (const float*)d_in[0];
  const float* feat1  = (const float*)d_in[1];
  const float* feat2  = (const float*)d_in[2];
  const float* feat3  = (const float*)d_in[3];
  const float* feat4  = (const float*)d_in[4];
  const float* orighw = (const float*)d_in[5];
  const float* W1     = (const float*)d_in[6];
  const float* b1     = (const float*)d_in[7];
  const float* W2     = (const float*)d_in[8];
  const float* b2     = (const float*)d_in[9];
  float* out = (float*)d_out;

  char* ws = (char*)d_ws;
  size_t off = 0;
  auto alloc = [&](size_t bytes) -> void* {
    void* p = ws + off;
    off = (off + bytes + 255) & ~(size_t)255;
    return p;
  };
  const int BN = NBATCH * NANCH;   // 204000
  float*  conf   = (float*)alloc((size_t)BN * 4);
  int*    cls    = (int*)  alloc((size_t)BN * 4);
  float*  gV     = (float*)alloc((size_t)BN * 4);
  int*    gI     = (int*)  alloc((size_t)BN * 4);
  float4* gBox   = (float4*)alloc((size_t)BN * 16);
  // zero-region: ghist + gcnt + ctr1 (contiguous; zeroed by conf_kernel)
  int*    ghist  = (int*)  alloc((size_t)NBATCH * NBINS * 4);   // 65536 B
  int*    gcnt   = (int*)  alloc((size_t)NBATCH * NBINS * 4);   // 65536 B
  int*    ctr1   = (int*)  alloc(256);
  const int zints = NBATCH * NBINS * 2 + 64;                    // 32832 ints
  float*  boxes  = (float*)alloc((size_t)NBATCH * 300 * 4 * 4);
  int*    keep   = (int*)  alloc((size_t)NBATCH * 300 * 4);
  __hip_bfloat16* fT1  = (__hip_bfloat16*)alloc((size_t)NBATCH * 6400 * 128 * 2);
  __hip_bfloat16* fT2  = (__hip_bfloat16*)alloc((size_t)NBATCH * 1600 * 256 * 2);
  __hip_bfloat16* fT3  = (__hip_bfloat16*)alloc((size_t)NBATCH * 400 * 512 * 2);
  __hip_bfloat16* fT4  = (__hip_bfloat16*)alloc((size_t)NBATCH * 100 * 1024 * 2);
  __hip_bfloat16* fmat = (__hip_bfloat16*)alloc((size_t)2400 * 1920 * 2);
  __hip_bfloat16* h1b  = (__hip_bfloat16*)alloc((size_t)2400 * 256 * 2);
  __hip_bfloat16* W1T  = (__hip_bfloat16*)alloc((size_t)256 * 1920 * 2);
  __hip_bfloat16* W2T  = (__hip_bfloat16*)alloc((size_t)256 * 256 * 2);

  conf_kernel<<<(BN + CONF_TILE - 1) / CONF_TILE, 256, 0, stream>>>(preds, conf, cls,
                                                                    ghist, zints, BN);

  scatter_kernel<<<SCAT_BLKS, 256, 0, stream>>>(conf, preds, cls, ghist, gcnt, ctr1,
                                                gV, gI, gBox);

  // fused nms (8 blocks @1024) + 4x 64x64 transpose tiles per 1024-thr block
  TransArgs ta;
  ta.src[0] = feat1; ta.dst[0] = fT1; ta.C[0] = 128;  ta.HW[0] = 6400;
  ta.src[1] = feat2; ta.dst[1] = fT2; ta.C[1] = 256;  ta.HW[1] = 1600;
  ta.src[2] = feat3; ta.dst[2] = fT3; ta.C[2] = 512;  ta.HW[2] = 400;
  ta.src[3] = feat4; ta.dst[3] = fT4; ta.C[3] = 1024; ta.HW[3] = 100;
  ta.src[4] = W1;    ta.dst[4] = W1T; ta.C[4] = 1920; ta.HW[4] = 256;
  ta.src[5] = W2;    ta.dst[5] = W2T; ta.C[5] = 256;  ta.HW[5] = 256;
  int n_tiles = 0;
  for (int s = 0; s < 6; ++s) {
    int txp = (ta.HW[s] + 63) / 64;
    int tyc = ta.C[s] / 64;
    int nbatch = (s < 4) ? NBATCH : 1;
    ta.tx[s] = txp;
    ta.tpb[s] = txp * tyc;
    ta.start[s] = n_tiles;
    n_tiles += ta.tpb[s] * nbatch;
  }
  nms_trans_kernel<<<8 + (n_tiles + 3) / 4, 1024, 0, stream>>>(ta, gV, gI, gBox, ghist,
                                                               boxes, keep, orighw, out,
                                                               n_tiles);

  roi_kernel<<<2400, 256, 0, stream>>>(boxes, fT1, fT2, fT3, fT4, fmat);
  gemm_tile_kernel<<<dim3(38, 4), 256, 0, stream>>>(fmat, W1T, b1, h1b, nullptr, nullptr,
                                                    2400, 256, 1920, 0, 0);
  gemm_tile_kernel<<<dim3(38, 4), 256, 0, stream>>>(h1b, W2T, b2, nullptr, out, keep,
                                                    2400, 256, 256, 260, 4);
}